// Round 5
// baseline (427.661 us; speedup 1.0000x reference)
//
#include <hip/hip_runtime.h>
#include <math.h>

#define N_   64
#define C_   512
#define HW_  1024
#define K_   64
#define ALPHA_ 50.0f
#define EPS_  1e-12f

// d_out float offsets
#define OUT_VLAD 0
#define OUT_SA   2097152     // N*K*C
#define OUT_FEAT 6291456     // + N*K*HW

// ws byte offsets (~26.7 MB)
#define WSB_WT    0           // fp32 [K][C]           131072 B
#define WSB_WNTB  131072      // bf16 [K][C]            65536 B
#define WSB_INVN  196608      // fp32 [N][HW]          262144 B
#define WSB_A     458752      // bf16 [N][K][HW]      8388608 B
#define WSB_SAP   8847360     // fp32 [N][64][64]      1048576 B (sumA partials)
#define WSB_PART  9895936     // fp32 2x[N][K][C]    16777216 B
#define PART_ELEMS 2097152    // floats per partial copy

typedef __attribute__((ext_vector_type(8))) __bf16 bf16x8;
typedef __attribute__((ext_vector_type(4))) float f32x4;
typedef __attribute__((ext_vector_type(8))) unsigned short ushort8v;

__device__ inline unsigned short f2bf(float f) {
    unsigned int u = __builtin_bit_cast(unsigned int, f);
    u = (u + 0x7FFFu + ((u >> 16) & 1u)) >> 16;
    return (unsigned short)u;
}
__device__ inline f32x4 mfma16(bf16x8 a, bf16x8 b, f32x4 c) {
    return __builtin_amdgcn_mfma_f32_16x16x32_bf16(a, b, c, 0, 0, 0);
}

// ---------------- K1: weight column norms -> wT fp32, wnTb bf16, both [K][C]
__global__ __launch_bounds__(256) void k1_weights(const float* __restrict__ W,
                                                  float* __restrict__ wT,
                                                  unsigned short* __restrict__ wnTb) {
    int k = blockIdx.x;
    int t = threadIdx.x;
    __shared__ float red[256];
    float s = 0.f;
    for (int c = t; c < C_; c += 256) { float w = W[c * K_ + k]; s += w * w; }
    red[t] = s;
    __syncthreads();
    for (int st = 128; st > 0; st >>= 1) {
        if (t < st) red[t] += red[t + st];
        __syncthreads();
    }
    float inv = 1.f / fmaxf(sqrtf(red[0]), EPS_);
    for (int c = t; c < C_; c += 256) {
        float w = W[c * K_ + k];
        wT[k * C_ + c]   = w;
        wnTb[k * C_ + c] = f2bf(w * inv);
    }
}

// ---------------- K23: fused normalize + feat write + GEMM1 + softmax
// 16-px tiles, grid 4096. 4 barriers total. B-frags direct from global W.
// Softmax + sumA fully in-register (shfl). Outputs: feat, invn, sa, Ab, sumA.
#define FPITCH 520   // bf16 elems per FshB row (1040 B, 16B-aligned)
#define LSP    20    // Ls pitch (floats)
__global__ __launch_bounds__(256, 3) void k23_fused(const float* __restrict__ x,
                                                    const unsigned short* __restrict__ wnTb,
                                                    const float* __restrict__ bias,
                                                    float* __restrict__ out,
                                                    float* __restrict__ invn,
                                                    unsigned short* __restrict__ Ab,
                                                    float* __restrict__ sumA_part) {
    __shared__ alignas(16) char smraw[32768 + 128 + 16640];   // 49536 B -> 3 blocks/CU
    float* Xs            = (float*)smraw;                     // [512 c][16 p] fp32, quad-XOR-swizzled
    float* Lls           = (float*)smraw;                     // phase4/5 overlay: logits [64][LSP]
    float* La            = Lls + 64 * LSP;                    //                  a      [64][LSP]
    float* invsh         = (float*)(smraw + 32768);           // [16]
    unsigned short* FshB = (unsigned short*)(smraw + 32896);  // [16 p][520] bf16 (A-operand)
    f32x4* red4          = (f32x4*)(smraw + 32896);           // phase-1 alias (256 B, dead before FshB)

    int b = blockIdx.x;
    int n = b >> 6, tile = b & 63;
    int hw0 = tile << 4;
    int t = threadIdx.x;
    int l = t & 63, w = t >> 6;
    int mr = l & 15, q = l >> 4;

    // ---- phase 1: float4 loads + square accumulate + swizzled LDS store
    const float* xb = x + (long)n * C_ * HW_ + hw0;
    int qv = t & 3, cbase = t >> 2;          // thread owns pixel-quad qv, c = cbase + 64j
    int qs = qv ^ (cbase & 3);               // XOR quad-slot swizzle
    f32x4 sq = (f32x4){0.f, 0.f, 0.f, 0.f};
    f32x4* Xs4 = (f32x4*)Xs;
#pragma unroll
    for (int j = 0; j < 8; ++j) {
        int c = cbase + 64 * j;
        f32x4 v = *(const f32x4*)(xb + (long)c * HW_ + qv * 4);
        sq += v * v;
        Xs4[c * 4 + qs] = v;
    }
    // wave-level reduce across lanes sharing qv (stride 4)
#pragma unroll
    for (int off = 4; off < 64; off <<= 1) {
        sq[0] += __shfl_down(sq[0], off, 64);
        sq[1] += __shfl_down(sq[1], off, 64);
        sq[2] += __shfl_down(sq[2], off, 64);
        sq[3] += __shfl_down(sq[3], off, 64);
    }
    if (l < 4) red4[w * 4 + l] = sq;         // [wave][qv] quad partials
    __syncthreads();
    if (t < 16) {                            // pixel p = t
        const float* redf = (const float*)red4;
        int qvv = t >> 2, comp = t & 3;
        float s = redf[(0 * 4 + qvv) * 4 + comp] + redf[(1 * 4 + qvv) * 4 + comp]
                + redf[(2 * 4 + qvv) * 4 + comp] + redf[(3 * 4 + qvv) * 4 + comp];
        float iv = 1.f / fmaxf(sqrtf(s), EPS_);
        invsh[t] = iv;
        invn[(long)n * HW_ + hw0 + t] = iv;
    }
    __syncthreads();

    // ---- phase 2: feat fp32 write (float4 along c) + FshB bf16 A-operand build
    {
        float* frow = out + OUT_FEAT + ((long)n * HW_ + hw0) * C_;
        int p = t & 15, cg = t >> 4;
        float iv = invsh[p];
        int ql = p >> 2, pr = p & 3;
#pragma unroll
        for (int j = 0; j < 8; ++j) {
            int c0 = 64 * j + cg * 4;
            float f0 = Xs[(c0    ) * 16 + ((ql ^ 0) << 2) + pr] * iv;
            float f1 = Xs[(c0 + 1) * 16 + ((ql ^ 1) << 2) + pr] * iv;
            float f2 = Xs[(c0 + 2) * 16 + ((ql ^ 2) << 2) + pr] * iv;
            float f3 = Xs[(c0 + 3) * 16 + ((ql ^ 3) << 2) + pr] * iv;
            f32x4 fv = (f32x4){f0, f1, f2, f3};
            *(f32x4*)(frow + (long)p * C_ + c0) = fv;
            uint2 u;
            u.x = (unsigned)f2bf(f0) | ((unsigned)f2bf(f1) << 16);
            u.y = (unsigned)f2bf(f2) | ((unsigned)f2bf(f3) << 16);
            *(uint2*)(FshB + p * FPITCH + c0) = u;
        }
    }
    __syncthreads();                          // FshB ready; Xs dead

    // ---- phase 3: GEMM1: A from FshB (LDS), B direct from global wnTb (L2-hot)
    f32x4 acc[4];
#pragma unroll
    for (int j = 0; j < 4; ++j) acc[j] = (f32x4){0.f, 0.f, 0.f, 0.f};
    {
        const unsigned short* wrow = wnTb + mr * C_;
#pragma unroll
        for (int ch = 0; ch < 4; ++ch) {
#pragma unroll
            for (int ks = 0; ks < 4; ++ks) {
                int co = ch * 128 + ks * 32 + q * 8;
                bf16x8 av = *(const bf16x8*)(FshB + mr * FPITCH + co);
                bf16x8 b0 = *(const bf16x8*)(wrow + co);
                bf16x8 b1 = *(const bf16x8*)(wrow + 16 * C_ + co);
                bf16x8 b2 = *(const bf16x8*)(wrow + 32 * C_ + co);
                bf16x8 b3 = *(const bf16x8*)(wrow + 48 * C_ + co);
                acc[0] = mfma16(av, b0, acc[0]);
                acc[1] = mfma16(av, b1, acc[1]);
                acc[2] = mfma16(av, b2, acc[2]);
                acc[3] = mfma16(av, b3, acc[3]);
            }
        }
    }

    // ---- phase 4: in-register softmax (px = q*4+r wave-local; kc = j*16+mr)
    float e[4][4], Mx[4], Sx[4], bz[4];
#pragma unroll
    for (int j = 0; j < 4; ++j) bz[j] = bias[j * 16 + mr];
#pragma unroll
    for (int r = 0; r < 4; ++r) {
        float m = -1e30f;
#pragma unroll
        for (int j = 0; j < 4; ++j) {
            float z = (acc[j][r] + bz[j]) * ALPHA_;
            e[j][r] = z;
            m = fmaxf(m, z);
        }
        m = fmaxf(m, __shfl_xor(m, 1, 64));
        m = fmaxf(m, __shfl_xor(m, 2, 64));
        m = fmaxf(m, __shfl_xor(m, 4, 64));
        m = fmaxf(m, __shfl_xor(m, 8, 64));
        Mx[r] = m;
        float s = 0.f;
#pragma unroll
        for (int j = 0; j < 4; ++j) {
            float ee = __expf(e[j][r] - m);
            e[j][r] = ee;
            s += ee;
        }
        s += __shfl_xor(s, 1, 64);
        s += __shfl_xor(s, 2, 64);
        s += __shfl_xor(s, 4, 64);
        s += __shfl_xor(s, 8, 64);
        Sx[r] = 1.f / s;
    }
    // dump logits + a to LDS (wave-partitioned by j == w) + sumA partials
#pragma unroll
    for (int j = 0; j < 4; ++j) {
        if (j == w) {
#pragma unroll
            for (int r = 0; r < 4; ++r) {
                Lls[(j * 16 + mr) * LSP + q * 4 + r] = acc[j][r];
                La [(j * 16 + mr) * LSP + q * 4 + r] = e[j][r] * Sx[r];
            }
            float ps = e[j][0] * Sx[0] + e[j][1] * Sx[1] + e[j][2] * Sx[2] + e[j][3] * Sx[3];
            ps += __shfl_xor(ps, 16, 64);
            ps += __shfl_xor(ps, 32, 64);
            if (q == 0)
                sumA_part[((long)n * 64 + tile) * 64 + j * 16 + mr] = ps;
        }
    }
    __syncthreads();

    // ---- phase 5: coalesced sa + Ab stores
    {
        float* sab = out + OUT_SA + (long)n * K_ * HW_ + hw0;
        unsigned short* Arow = Ab + (long)n * K_ * HW_ + hw0;
        int kc = t >> 2, p0 = (t & 3) * 4;
        f32x4 v = *(f32x4*)(Lls + kc * LSP + p0);
        *(f32x4*)(sab + (long)kc * HW_ + p0) = v;
        f32x4 a = *(f32x4*)(La + kc * LSP + p0);
        uint2 u;
        u.x = (unsigned)f2bf(a[0]) | ((unsigned)f2bf(a[1]) << 16);
        u.y = (unsigned)f2bf(a[2]) | ((unsigned)f2bf(a[3]) << 16);
        *(uint2*)(Arow + (long)kc * HW_ + p0) = u;
    }
}

// ---------------- K4: barrier-free MFMA GEMM2 vlad_raw = A . (x*invn)
// All operands direct from global (Ab/W-tile L2-hot, x HBM once); cvt in regs.
__global__ __launch_bounds__(256, 4) void k4_vlad(const float* __restrict__ x,
                                                  const float* __restrict__ invn,
                                                  const unsigned short* __restrict__ Ab,
                                                  float* __restrict__ part) {
    __shared__ float invs[512];
    int b  = blockIdx.x;
    int n  = b >> 4;
    int r  = b & 15;
    int c_off  = (r & 7) * 64;
    int hh     = r >> 3;
    int h_base = hh * 512;
    int t = threadIdx.x;
    int l = t & 63, w = t >> 6;
    int mr = l & 15, q = l >> 4;
    int kcb = (w >> 1) * 32, cb = (w & 1) * 32;

    invs[t]       = invn[(long)n * HW_ + h_base + t];
    invs[t + 256] = invn[(long)n * HW_ + h_base + 256 + t];
    __syncthreads();

    f32x4 acc[2][2];
#pragma unroll
    for (int i = 0; i < 2; ++i)
#pragma unroll
        for (int j = 0; j < 2; ++j) acc[i][j] = (f32x4){0.f, 0.f, 0.f, 0.f};

    const unsigned short* Arow0 = Ab + (long)n * K_ * HW_ + (long)(kcb + mr) * HW_ + h_base;
    const unsigned short* Arow1 = Arow0 + 16 * HW_;
    const float* xr0 = x + ((long)n * C_ + c_off + cb + mr) * HW_ + h_base;
    const float* xr1 = xr0 + 16 * HW_;

    for (int ch = 0; ch < 8; ++ch) {
#pragma unroll
        for (int ks = 0; ks < 2; ++ks) {
            int ko = ch * 64 + ks * 32 + q * 8;
            bf16x8 a0 = *(const bf16x8*)(Arow0 + ko);
            bf16x8 a1 = *(const bf16x8*)(Arow1 + ko);
            const float* iv = invs + ko;
            float4 v0 = *(const float4*)(xr0 + ko);
            float4 v1 = *(const float4*)(xr0 + ko + 4);
            ushort8v p0;
            p0[0] = f2bf(v0.x * iv[0]); p0[1] = f2bf(v0.y * iv[1]);
            p0[2] = f2bf(v0.z * iv[2]); p0[3] = f2bf(v0.w * iv[3]);
            p0[4] = f2bf(v1.x * iv[4]); p0[5] = f2bf(v1.y * iv[5]);
            p0[6] = f2bf(v1.z * iv[6]); p0[7] = f2bf(v1.w * iv[7]);
            bf16x8 b0 = __builtin_bit_cast(bf16x8, p0);
            float4 v2 = *(const float4*)(xr1 + ko);
            float4 v3 = *(const float4*)(xr1 + ko + 4);
            ushort8v p1;
            p1[0] = f2bf(v2.x * iv[0]); p1[1] = f2bf(v2.y * iv[1]);
            p1[2] = f2bf(v2.z * iv[2]); p1[3] = f2bf(v2.w * iv[3]);
            p1[4] = f2bf(v3.x * iv[4]); p1[5] = f2bf(v3.y * iv[5]);
            p1[6] = f2bf(v3.z * iv[6]); p1[7] = f2bf(v3.w * iv[7]);
            bf16x8 b1 = __builtin_bit_cast(bf16x8, p1);
            acc[0][0] = mfma16(a0, b0, acc[0][0]);
            acc[1][0] = mfma16(a1, b0, acc[1][0]);
            acc[0][1] = mfma16(a0, b1, acc[0][1]);
            acc[1][1] = mfma16(a1, b1, acc[1][1]);
        }
    }
    float* pb = part + (long)hh * PART_ELEMS + (long)n * K_ * C_ + c_off;
#pragma unroll
    for (int i = 0; i < 2; ++i)
#pragma unroll
        for (int j = 0; j < 2; ++j)
#pragma unroll
            for (int rr = 0; rr < 4; ++rr) {
                int kc = kcb + i * 16 + q * 4 + rr;
                int c  = cb + j * 16 + mr;
                pb[(long)kc * C_ + c] = acc[i][j][rr];
            }
}

// ---------------- K5: combine 2 partials, subtract sumA*W, intra-normalize
__global__ __launch_bounds__(256) void k5_norm(const float* __restrict__ part,
                                               const float* __restrict__ sumA_part,
                                               const float* __restrict__ wT,
                                               float* __restrict__ vlad) {
    __shared__ float red[256];
    __shared__ float sred[64];
    int row = blockIdx.x;        // n*64 + kc
    int kc  = row & 63;
    int n   = row >> 6;
    int t   = threadIdx.x;
    if (t < 64) sred[t] = sumA_part[((long)n * 64 + t) * 64 + kc];
    __syncthreads();
    if (t < 16) sred[t] = sred[t] + sred[t + 16] + sred[t + 32] + sred[t + 48];
    __syncthreads();
    if (t < 4) sred[t] = sred[t] + sred[t + 4] + sred[t + 8] + sred[t + 12];
    __syncthreads();
    float sA = sred[0] + sred[1] + sred[2] + sred[3];
    long base = (long)row * C_;
    float v0, v1;
    {
        int c = t;
        float s = part[base + c] + part[PART_ELEMS + base + c];
        v0 = s - sA * wT[kc * C_ + c];
    }
    {
        int c = t + 256;
        float s = part[base + c] + part[PART_ELEMS + base + c];
        v1 = s - sA * wT[kc * C_ + c];
    }
    red[t] = v0 * v0 + v1 * v1;
    __syncthreads();
    for (int st = 128; st > 0; st >>= 1) {
        if (t < st) red[t] += red[t + st];
        __syncthreads();
    }
    float inv = 1.f / fmaxf(sqrtf(red[0]), EPS_);
    vlad[base + t]       = v0 * inv;
    vlad[base + t + 256] = v1 * inv;
}

extern "C" void kernel_launch(void* const* d_in, const int* in_sizes, int n_in,
                              void* d_out, int out_size, void* d_ws, size_t ws_size,
                              hipStream_t stream) {
    const float* x    = (const float*)d_in[0];
    const float* W    = (const float*)d_in[1];
    const float* bias = (const float*)d_in[2];
    float* out = (float*)d_out;
    char* wsb  = (char*)d_ws;

    float* wT            = (float*)(wsb + WSB_WT);
    unsigned short* wnTb = (unsigned short*)(wsb + WSB_WNTB);
    float* invn          = (float*)(wsb + WSB_INVN);
    unsigned short* Ab   = (unsigned short*)(wsb + WSB_A);
    float* sumA_part     = (float*)(wsb + WSB_SAP);
    float* part          = (float*)(wsb + WSB_PART);

    float* vlad = out + OUT_VLAD;

    hipLaunchKernelGGL(k1_weights, dim3(64),   dim3(256), 0, stream, W, wT, wnTb);
    hipLaunchKernelGGL(k23_fused,  dim3(4096), dim3(256), 0, stream, x, wnTb, bias, out, invn, Ab, sumA_part);
    hipLaunchKernelGGL(k4_vlad,    dim3(1024), dim3(256), 0, stream, x, invn, Ab, part);
    hipLaunchKernelGGL(k5_norm,    dim3(4096), dim3(256), 0, stream, part, sumA_part, wT, vlad);
}